// Round 5
// baseline (369.250 us; speedup 1.0000x reference)
//
#include <hip/hip_runtime.h>
#include <hip/hip_bf16.h>
#include <cstdint>
#include <cstddef>

typedef unsigned short u16;
typedef unsigned int u32;
using f32x4  = __attribute__((ext_vector_type(4))) float;
using bf16x8 = __attribute__((ext_vector_type(8))) short;

__device__ __forceinline__ u16 f2bf(float f) {
    u32 u = __builtin_bit_cast(u32, f);
    u32 r = u + 0x7fffu + ((u >> 16) & 1u);
    return (u16)(r >> 16);
}

// async global->LDS, 16B per lane; LDS dest = wave-uniform base + lane*16 (linear!)
__device__ __forceinline__ void gload16(const u16* g, u16* l) {
    __builtin_amdgcn_global_load_lds(
        (const __attribute__((address_space(1))) void*)g,
        (__attribute__((address_space(3))) void*)l,
        16, 0, 0);
}

// ---------------- fp32 -> bf16 elementwise convert (vectorized) ----------------
__global__ void k_convert(const float* __restrict__ src, u16* __restrict__ dst, int n4) {
    int i = blockIdx.x * blockDim.x + threadIdx.x;
    int stride = gridDim.x * blockDim.x;
    for (; i < n4; i += stride) {
        float4 v = ((const float4*)src)[i];
        ushort4 o;
        o.x = f2bf(v.x); o.y = f2bf(v.y); o.z = f2bf(v.z); o.w = f2bf(v.w);
        ((ushort4*)dst)[i] = o;
    }
}

// ---------------- fp32 [K][N] -> bf16 [N][K] tiled transpose-convert ----------------
__global__ void k_tconv(const float* __restrict__ src, u16* __restrict__ dst, int K, int N) {
    __shared__ float tile[32][33];
    int nb = blockIdx.x * 32, kb = blockIdx.y * 32;
    int tx = threadIdx.x, ty = threadIdx.y;  // 32 x 8
    #pragma unroll
    for (int j = 0; j < 32; j += 8)
        tile[ty + j][tx] = src[(size_t)(kb + ty + j) * N + nb + tx];
    __syncthreads();
    #pragma unroll
    for (int j = 0; j < 32; j += 8)
        dst[(size_t)(nb + ty + j) * K + kb + tx] = f2bf(tile[tx][ty + j]);
}

// ---------------- shared 128x128-tile bf16 MFMA mainloop (K=1024, both operands [*][1024]) ----------------
// Staging via global_load_lds width=16 (m97 pattern). LDS is linear [128][32] u16:
// chunk q (16B) lives at byte q*16, q = row*4 + c. Wave w stages q in [w*128, w*128+128).
__device__ __forceinline__ void gemm128_mainloop(const u16* __restrict__ A,
                                                 const u16* __restrict__ Bt,
                                                 int m0, int n0, f32x4 (&acc)[4][4]) {
    __shared__ __align__(16) u16 As[128][32];
    __shared__ __align__(16) u16 Bs[128][32];
    const int t = threadIdx.x;
    const int lane = t & 63, wave = t >> 6;
    const int wr = wave >> 1, wc = wave & 1;
    const int g = lane >> 4, lr = lane & 15;

    #pragma unroll
    for (int mi = 0; mi < 4; mi++)
        #pragma unroll
        for (int ni = 0; ni < 4; ni++)
            acc[mi][ni] = (f32x4){0.f, 0.f, 0.f, 0.f};

    // two 16B chunks per thread per buffer
    const int q0 = wave * 128 + lane;      // issue 0
    const int q1 = q0 + 64;                // issue 1
    const int r0 = q0 >> 2, c0 = (q0 & 3) * 8;
    const int r1 = q1 >> 2, c1 = (q1 & 3) * 8;
    u16* ldsA0 = &As[0][0] + wave * 1024;  // wave-uniform base (bytes: wave*2048)
    u16* ldsA1 = ldsA0 + 512;
    u16* ldsB0 = &Bs[0][0] + wave * 1024;
    u16* ldsB1 = ldsB0 + 512;
    const u16* gA0 = A  + (size_t)(m0 + r0) * 1024 + c0;
    const u16* gA1 = A  + (size_t)(m0 + r1) * 1024 + c1;
    const u16* gB0 = Bt + (size_t)(n0 + r0) * 1024 + c0;
    const u16* gB1 = Bt + (size_t)(n0 + r1) * 1024 + c1;

    for (int kt = 0; kt < 1024; kt += 32) {
        __syncthreads();   // prior iteration's ds_reads done before overwrite
        gload16(gA0 + kt, ldsA0);
        gload16(gA1 + kt, ldsA1);
        gload16(gB0 + kt, ldsB0);
        gload16(gB1 + kt, ldsB1);
        __syncthreads();   // compiler drains vmcnt(0) before barrier -> data ready
        bf16x8 af[4], bfr[4];
        #pragma unroll
        for (int mi = 0; mi < 4; mi++)
            af[mi] = *(const bf16x8*)&As[wr * 64 + mi * 16 + lr][g * 8];
        #pragma unroll
        for (int ni = 0; ni < 4; ni++)
            bfr[ni] = *(const bf16x8*)&Bs[wc * 64 + ni * 16 + lr][g * 8];
        #pragma unroll
        for (int mi = 0; mi < 4; mi++)
            #pragma unroll
            for (int ni = 0; ni < 4; ni++)
                acc[mi][ni] = __builtin_amdgcn_mfma_f32_16x16x32_bf16(af[mi], bfr[ni], acc[mi][ni], 0, 0, 0);
    }
}

// ---------------- QKV GEMM: C = X@W + b + lora, scatter to Q (x0.125), K, V^T as bf16 ----------------
__global__ __launch_bounds__(256) void k_gemm_qkv(const u16* __restrict__ Xb, const u16* __restrict__ Wab,
                                                  const float* __restrict__ lora, const float* __restrict__ b_attn,
                                                  u16* __restrict__ Qb, u16* __restrict__ Kb, u16* __restrict__ Vt) {
    f32x4 acc[4][4];
    const int m0 = blockIdx.y * 128, n0 = blockIdx.x * 128;
    gemm128_mainloop(Xb, Wab, m0, n0, acc);
    const int lane = threadIdx.x & 63, wave = threadIdx.x >> 6;
    const int wr = wave >> 1, wc = wave & 1, g = lane >> 4, lr = lane & 15;
    #pragma unroll
    for (int mi = 0; mi < 4; mi++)
        #pragma unroll
        for (int ni = 0; ni < 4; ni++)
            #pragma unroll
            for (int r = 0; r < 4; r++) {
                int m = m0 + wr * 64 + mi * 16 + g * 4 + r;
                int n = n0 + wc * 64 + ni * 16 + lr;
                float v = acc[mi][ni][r] + b_attn[n] + lora[(size_t)m * 3072 + n];
                int which = n >> 10, rem = n & 1023, h = rem >> 6, hd = rem & 63;
                int b = m >> 11, s = m & 2047;
                size_t idx = ((size_t)(b * 16 + h) * 2048 + s) * 64 + hd;
                if (which == 0)      Qb[idx] = f2bf(v * 0.125f);   // fold 1/sqrt(64), exact pow2
                else if (which == 1) Kb[idx] = f2bf(v);
                else Vt[((size_t)(b * 16 + h) * 64 + hd) * 2048 + s] = f2bf(v);
            }
}

// ---------------- causal flash attention: 4 waves x 16 q-rows, KV tiles of 64 ----------------
// T14 async-STAGE split: next tile's K/V prefetched into regs during compute.
__global__ __launch_bounds__(256) void k_attn(const u16* __restrict__ Qb, const u16* __restrict__ Kb,
                                              const u16* __restrict__ Vt, u16* __restrict__ Ao) {
    __shared__ __align__(16) u16 Ks[64][72];
    __shared__ __align__(16) u16 Vs[64][72];     // Vs[d][key]
    __shared__ __align__(16) u16 Ps[4][16][72];  // per-wave P tile [q][key] (wave-private)
    const int qt = blockIdx.x, bh = blockIdx.y;
    const int t = threadIdx.x, wave = t >> 6, lane = t & 63;
    const int g = lane >> 4, lr = lane & 15;
    const size_t bhO = (size_t)bh * (2048 * 64);
    const int q0 = qt * 64;
    const int qrow = q0 + wave * 16 + lr;

    bf16x8 qf0 = *(const bf16x8*)(Qb + bhO + (size_t)qrow * 64 + g * 8);
    bf16x8 qf1 = *(const bf16x8*)(Qb + bhO + (size_t)qrow * 64 + 32 + g * 8);

    f32x4 accO[4];
    float m_run[4], l_run[4];
    #pragma unroll
    for (int i = 0; i < 4; i++) { accO[i] = (f32x4){0.f,0.f,0.f,0.f}; m_run[i] = -INFINITY; l_run[i] = 0.f; }

    const int sr0 = t >> 3,         sj0 = t & 7;
    const int sr1 = (t + 256) >> 3, sj1 = (t + 256) & 7;
    const u16* gK0 = Kb + bhO + (size_t)sr0 * 64 + sj0 * 8;     // + kt*64*64 per tile (row offset kt*64)
    const u16* gK1 = Kb + bhO + (size_t)sr1 * 64 + sj1 * 8;
    const u16* gV0 = Vt + bhO + (size_t)sr0 * 2048 + sj0 * 8;   // + kt*64 per tile (key offset)
    const u16* gV1 = Vt + bhO + (size_t)sr1 * 2048 + sj1 * 8;

    // prologue: prefetch tile 0 into registers
    uint4 pk0 = *(const uint4*)(gK0);
    uint4 pk1 = *(const uint4*)(gK1);
    uint4 pv0 = *(const uint4*)(gV0);
    uint4 pv1 = *(const uint4*)(gV1);

    for (int kt = 0; kt <= qt; ++kt) {
        const int k0 = kt * 64;
        __syncthreads();  // previous iteration's LDS reads done before restaging
        *(uint4*)&Ks[sr0][sj0 * 8] = pk0;
        *(uint4*)&Ks[sr1][sj1 * 8] = pk1;
        *(uint4*)&Vs[sr0][sj0 * 8] = pv0;
        *(uint4*)&Vs[sr1][sj1 * 8] = pv1;
        __syncthreads();

        if (kt < qt) {   // issue next tile's loads now; latency hides under compute below
            const size_t kn = (size_t)(k0 + 64);
            pk0 = *(const uint4*)(gK0 + kn * 64);
            pk1 = *(const uint4*)(gK1 + kn * 64);
            pv0 = *(const uint4*)(gV0 + kn);
            pv1 = *(const uint4*)(gV1 + kn);
        }

        // scores: S = (Q*0.125) @ K^T, C-layout col=key(lr), row=q(g*4+r)
        f32x4 sc[4];
        #pragma unroll
        for (int ni = 0; ni < 4; ni++) {
            bf16x8 kf0 = *(const bf16x8*)&Ks[ni * 16 + lr][g * 8];
            bf16x8 kf1 = *(const bf16x8*)&Ks[ni * 16 + lr][32 + g * 8];
            f32x4 z = {0.f, 0.f, 0.f, 0.f};
            z = __builtin_amdgcn_mfma_f32_16x16x32_bf16(qf0, kf0, z, 0, 0, 0);
            z = __builtin_amdgcn_mfma_f32_16x16x32_bf16(qf1, kf1, z, 0, 0, 0);
            sc[ni] = z;
        }
        if (kt == qt) {  // only the diagonal tile needs masking
            #pragma unroll
            for (int ni = 0; ni < 4; ni++)
                #pragma unroll
                for (int r = 0; r < 4; r++) {
                    int kidx = k0 + ni * 16 + lr;
                    int qi = q0 + wave * 16 + g * 4 + r;
                    if (kidx > qi) sc[ni][r] = -INFINITY;
                }
        }
        // online softmax: row r lives in 16 lanes of this lane-group
        #pragma unroll
        for (int r = 0; r < 4; r++) {
            float mx = fmaxf(fmaxf(sc[0][r], sc[1][r]), fmaxf(sc[2][r], sc[3][r]));
            #pragma unroll
            for (int d = 1; d < 16; d <<= 1) mx = fmaxf(mx, __shfl_xor(mx, d, 64));
            float mnew = fmaxf(m_run[r], mx);
            float fsc = __expf(m_run[r] - mnew);   // first tile: exp(-inf)=0
            float ls = 0.f;
            #pragma unroll
            for (int ni = 0; ni < 4; ni++) {
                float p = __expf(sc[ni][r] - mnew);
                sc[ni][r] = p;
                ls += p;
            }
            #pragma unroll
            for (int d = 1; d < 16; d <<= 1) ls += __shfl_xor(ls, d, 64);
            #pragma unroll
            for (int di = 0; di < 4; di++) accO[di][r] *= fsc;
            m_run[r] = mnew;
            l_run[r] = l_run[r] * fsc + ls;
        }
        // P (C-layout) -> LDS (wave-private slice; same-wave DS ops are ordered, no barrier)
        #pragma unroll
        for (int ni = 0; ni < 4; ni++)
            #pragma unroll
            for (int r = 0; r < 4; r++)
                Ps[wave][g * 4 + r][ni * 16 + lr] = f2bf(sc[ni][r]);
        // O += P @ V   (A row = q(lr), B col = d(lr), k = key)
        #pragma unroll
        for (int e = 0; e < 2; e++) {
            bf16x8 pa = *(const bf16x8*)&Ps[wave][lr][e * 32 + g * 8];
            #pragma unroll
            for (int di = 0; di < 4; di++) {
                bf16x8 vb = *(const bf16x8*)&Vs[di * 16 + lr][e * 32 + g * 8];
                accO[di] = __builtin_amdgcn_mfma_f32_16x16x32_bf16(pa, vb, accO[di], 0, 0, 0);
            }
        }
    }
    const int b = bh >> 4, h = bh & 15;
    #pragma unroll
    for (int di = 0; di < 4; di++)
        #pragma unroll
        for (int r = 0; r < 4; r++) {
            int s = q0 + wave * 16 + g * 4 + r;
            float v = accO[di][r] / l_run[r];
            Ao[((size_t)(b * 2048 + s)) * 1024 + h * 64 + di * 16 + lr] = f2bf(v);
        }
}

// ---------------- output projection: out = Ao @ Wp + b (fp32 out) ----------------
__global__ __launch_bounds__(256) void k_gemm_proj(const u16* __restrict__ Ao, const u16* __restrict__ Wpb,
                                                   const float* __restrict__ b_proj, float* __restrict__ out) {
    f32x4 acc[4][4];
    const int m0 = blockIdx.y * 128, n0 = blockIdx.x * 128;
    gemm128_mainloop(Ao, Wpb, m0, n0, acc);
    const int lane = threadIdx.x & 63, wave = threadIdx.x >> 6;
    const int wr = wave >> 1, wc = wave & 1, g = lane >> 4, lr = lane & 15;
    #pragma unroll
    for (int mi = 0; mi < 4; mi++)
        #pragma unroll
        for (int ni = 0; ni < 4; ni++)
            #pragma unroll
            for (int r = 0; r < 4; r++) {
                int m = m0 + wr * 64 + mi * 16 + g * 4 + r;
                int n = n0 + wc * 64 + ni * 16 + lr;
                out[(size_t)m * 1024 + n] = acc[mi][ni][r] + b_proj[n];
            }
}

extern "C" void kernel_launch(void* const* d_in, const int* in_sizes, int n_in,
                              void* d_out, int out_size, void* d_ws, size_t ws_size,
                              hipStream_t stream) {
    const float* hidden = (const float*)d_in[0];
    const float* lora   = (const float*)d_in[1];
    const float* w_attn = (const float*)d_in[2];
    const float* b_attn = (const float*)d_in[3];
    const float* w_proj = (const float*)d_in[4];
    const float* b_proj = (const float*)d_in[5];
    float* out = (float*)d_out;

    char* ws = (char*)d_ws;
    u16* Xb  = (u16*)(ws + 0x0);        // 4096x1024 bf16 (reused as Ao after QKV GEMM)
    u16* Wab = (u16*)(ws + 0x800000);   // w_attn^T  [3072][1024] bf16
    u16* Wpb = (u16*)(ws + 0xE00000);   // w_proj^T  [1024][1024] bf16
    u16* Qb  = (u16*)(ws + 0x1000000);  // [B,H,S,64] bf16 (pre-scaled by 0.125)
    u16* Kb  = (u16*)(ws + 0x1800000);  // [B,H,S,64] bf16
    u16* Vt  = (u16*)(ws + 0x2000000);  // [B,H,64,S] bf16
    u16* Ao  = Xb;                      // merged attention output [B,S,1024] bf16

    k_convert<<<1024, 256, 0, stream>>>(hidden, Xb, (2 * 2048 * 1024) / 4);
    k_tconv<<<dim3(96, 32), dim3(32, 8), 0, stream>>>(w_attn, Wab, 1024, 3072);
    k_tconv<<<dim3(32, 32), dim3(32, 8), 0, stream>>>(w_proj, Wpb, 1024, 1024);
    k_gemm_qkv<<<dim3(24, 32), 256, 0, stream>>>(Xb, Wab, lora, b_attn, Qb, Kb, Vt);
    k_attn<<<dim3(32, 32), 256, 0, stream>>>(Qb, Kb, Vt, Ao);
    k_gemm_proj<<<dim3(8, 32), 256, 0, stream>>>(Ao, Wpb, b_proj, out);
}

// Round 6
// 318.385 us; speedup vs baseline: 1.1598x; 1.1598x over previous
//
#include <hip/hip_runtime.h>
#include <hip/hip_bf16.h>
#include <cstdint>
#include <cstddef>

typedef unsigned short u16;
typedef unsigned int u32;
using f32x4  = __attribute__((ext_vector_type(4))) float;
using bf16x8 = __attribute__((ext_vector_type(8))) short;

__device__ __forceinline__ u16 f2bf(float f) {
    u32 u = __builtin_bit_cast(u32, f);
    u32 r = u + 0x7fffu + ((u >> 16) & 1u);
    return (u16)(r >> 16);
}

// async global->LDS, 16B per lane; LDS dest = wave-uniform base + lane*16 (linear!)
__device__ __forceinline__ void gload16(const u16* g, u16* l) {
    __builtin_amdgcn_global_load_lds(
        (const __attribute__((address_space(1))) void*)g,
        (__attribute__((address_space(3))) void*)l,
        16, 0, 0);
}

// ---------------- fp32 -> bf16 elementwise convert (vectorized) ----------------
__global__ void k_convert(const float* __restrict__ src, u16* __restrict__ dst, int n4) {
    int i = blockIdx.x * blockDim.x + threadIdx.x;
    int stride = gridDim.x * blockDim.x;
    for (; i < n4; i += stride) {
        float4 v = ((const float4*)src)[i];
        ushort4 o;
        o.x = f2bf(v.x); o.y = f2bf(v.y); o.z = f2bf(v.z); o.w = f2bf(v.w);
        ((ushort4*)dst)[i] = o;
    }
}

// ---------------- fp32 [K][N] -> bf16 [N][K] tiled transpose-convert ----------------
__global__ void k_tconv(const float* __restrict__ src, u16* __restrict__ dst, int K, int N) {
    __shared__ float tile[32][33];
    int nb = blockIdx.x * 32, kb = blockIdx.y * 32;
    int tx = threadIdx.x, ty = threadIdx.y;  // 32 x 8
    #pragma unroll
    for (int j = 0; j < 32; j += 8)
        tile[ty + j][tx] = src[(size_t)(kb + ty + j) * N + nb + tx];
    __syncthreads();
    #pragma unroll
    for (int j = 0; j < 32; j += 8)
        dst[(size_t)(nb + ty + j) * K + kb + tx] = f2bf(tile[tx][ty + j]);
}

// ---------------- shared 128x128-tile bf16 MFMA mainloop (K=1024, both operands [*][1024]) ----------------
// Staging via global_load_lds width=16 (m97 pattern). LDS is linear [128][32] u16.
__device__ __forceinline__ void gemm128_mainloop(const u16* __restrict__ A,
                                                 const u16* __restrict__ Bt,
                                                 int m0, int n0, f32x4 (&acc)[4][4]) {
    __shared__ __align__(16) u16 As[128][32];
    __shared__ __align__(16) u16 Bs[128][32];
    const int t = threadIdx.x;
    const int lane = t & 63, wave = t >> 6;
    const int wr = wave >> 1, wc = wave & 1;
    const int g = lane >> 4, lr = lane & 15;

    #pragma unroll
    for (int mi = 0; mi < 4; mi++)
        #pragma unroll
        for (int ni = 0; ni < 4; ni++)
            acc[mi][ni] = (f32x4){0.f, 0.f, 0.f, 0.f};

    const int q0 = wave * 128 + lane;
    const int q1 = q0 + 64;
    const int r0 = q0 >> 2, c0 = (q0 & 3) * 8;
    const int r1 = q1 >> 2, c1 = (q1 & 3) * 8;
    u16* ldsA0 = &As[0][0] + wave * 1024;
    u16* ldsA1 = ldsA0 + 512;
    u16* ldsB0 = &Bs[0][0] + wave * 1024;
    u16* ldsB1 = ldsB0 + 512;
    const u16* gA0 = A  + (size_t)(m0 + r0) * 1024 + c0;
    const u16* gA1 = A  + (size_t)(m0 + r1) * 1024 + c1;
    const u16* gB0 = Bt + (size_t)(n0 + r0) * 1024 + c0;
    const u16* gB1 = Bt + (size_t)(n0 + r1) * 1024 + c1;

    for (int kt = 0; kt < 1024; kt += 32) {
        __syncthreads();
        gload16(gA0 + kt, ldsA0);
        gload16(gA1 + kt, ldsA1);
        gload16(gB0 + kt, ldsB0);
        gload16(gB1 + kt, ldsB1);
        __syncthreads();
        bf16x8 af[4], bfr[4];
        #pragma unroll
        for (int mi = 0; mi < 4; mi++)
            af[mi] = *(const bf16x8*)&As[wr * 64 + mi * 16 + lr][g * 8];
        #pragma unroll
        for (int ni = 0; ni < 4; ni++)
            bfr[ni] = *(const bf16x8*)&Bs[wc * 64 + ni * 16 + lr][g * 8];
        #pragma unroll
        for (int mi = 0; mi < 4; mi++)
            #pragma unroll
            for (int ni = 0; ni < 4; ni++)
                acc[mi][ni] = __builtin_amdgcn_mfma_f32_16x16x32_bf16(af[mi], bfr[ni], acc[mi][ni], 0, 0, 0);
    }
}

// ---------------- QKV GEMM: C = X@W + b + lora, scatter to Q (x0.125), K, V^T as bf16 ----------------
__global__ __launch_bounds__(256) void k_gemm_qkv(const u16* __restrict__ Xb, const u16* __restrict__ Wab,
                                                  const float* __restrict__ lora, const float* __restrict__ b_attn,
                                                  u16* __restrict__ Qb, u16* __restrict__ Kb, u16* __restrict__ Vt) {
    f32x4 acc[4][4];
    const int m0 = blockIdx.y * 128, n0 = blockIdx.x * 128;
    gemm128_mainloop(Xb, Wab, m0, n0, acc);
    const int lane = threadIdx.x & 63, wave = threadIdx.x >> 6;
    const int wr = wave >> 1, wc = wave & 1, g = lane >> 4, lr = lane & 15;
    #pragma unroll
    for (int mi = 0; mi < 4; mi++)
        #pragma unroll
        for (int ni = 0; ni < 4; ni++)
            #pragma unroll
            for (int r = 0; r < 4; r++) {
                int m = m0 + wr * 64 + mi * 16 + g * 4 + r;
                int n = n0 + wc * 64 + ni * 16 + lr;
                float v = acc[mi][ni][r] + b_attn[n] + lora[(size_t)m * 3072 + n];
                int which = n >> 10, rem = n & 1023, h = rem >> 6, hd = rem & 63;
                int b = m >> 11, s = m & 2047;
                size_t idx = ((size_t)(b * 16 + h) * 2048 + s) * 64 + hd;
                if (which == 0)      Qb[idx] = f2bf(v * 0.125f);   // fold 1/sqrt(64), exact pow2
                else if (which == 1) Kb[idx] = f2bf(v);
                else Vt[((size_t)(b * 16 + h) * 64 + hd) * 2048 + s] = f2bf(v);
            }
}

// ---------------- per-KV-tile attention compute for one wave's 16 q-rows ----------------
__device__ __forceinline__ void attn_tile(const u16 (*Ks)[72], const u16 (*Vs)[72], u16 (*Ps)[72],
                                          int g, int lr, int rowq /*q0+wave*16*/, int k0, bool diag,
                                          bf16x8 qf0, bf16x8 qf1,
                                          f32x4 (&accO)[4], float (&m_run)[4], float (&l_run)[4]) {
    // scores: S = (Q*0.125) @ K^T, C-layout col=key(lr), row=q(g*4+r)
    f32x4 sc[4];
    #pragma unroll
    for (int ni = 0; ni < 4; ni++) {
        bf16x8 kf0 = *(const bf16x8*)&Ks[ni * 16 + lr][g * 8];
        bf16x8 kf1 = *(const bf16x8*)&Ks[ni * 16 + lr][32 + g * 8];
        f32x4 z = {0.f, 0.f, 0.f, 0.f};
        z = __builtin_amdgcn_mfma_f32_16x16x32_bf16(qf0, kf0, z, 0, 0, 0);
        z = __builtin_amdgcn_mfma_f32_16x16x32_bf16(qf1, kf1, z, 0, 0, 0);
        sc[ni] = z;
    }
    if (diag) {  // only the diagonal tile needs masking
        #pragma unroll
        for (int ni = 0; ni < 4; ni++)
            #pragma unroll
            for (int r = 0; r < 4; r++)
                if (k0 + ni * 16 + lr > rowq + g * 4 + r) sc[ni][r] = -INFINITY;
    }
    // online softmax: row r lives in the 16 lanes of this lane-group
    #pragma unroll
    for (int r = 0; r < 4; r++) {
        float mx = fmaxf(fmaxf(sc[0][r], sc[1][r]), fmaxf(sc[2][r], sc[3][r]));
        #pragma unroll
        for (int d = 1; d < 16; d <<= 1) mx = fmaxf(mx, __shfl_xor(mx, d, 64));
        float mnew = fmaxf(m_run[r], mx);
        float fsc = __expf(m_run[r] - mnew);   // first tile: exp(-inf)=0
        float ls = 0.f;
        #pragma unroll
        for (int ni = 0; ni < 4; ni++) {
            float p = __expf(sc[ni][r] - mnew);
            sc[ni][r] = p;
            ls += p;
        }
        #pragma unroll
        for (int d = 1; d < 16; d <<= 1) ls += __shfl_xor(ls, d, 64);
        #pragma unroll
        for (int di = 0; di < 4; di++) accO[di][r] *= fsc;
        m_run[r] = mnew;
        l_run[r] = l_run[r] * fsc + ls;
    }
    // P (C-layout) -> LDS (wave-private slice; same-wave DS ops ordered, no barrier)
    #pragma unroll
    for (int ni = 0; ni < 4; ni++)
        #pragma unroll
        for (int r = 0; r < 4; r++)
            Ps[g * 4 + r][ni * 16 + lr] = f2bf(sc[ni][r]);
    // O += P @ V   (A row = q(lr), B col = d(lr), k = key)
    #pragma unroll
    for (int e = 0; e < 2; e++) {
        bf16x8 pa = *(const bf16x8*)&Ps[lr][e * 32 + g * 8];
        #pragma unroll
        for (int di = 0; di < 4; di++) {
            bf16x8 vb = *(const bf16x8*)&Vs[di * 16 + lr][e * 32 + g * 8];
            accO[di] = __builtin_amdgcn_mfma_f32_16x16x32_bf16(pa, vb, accO[di], 0, 0, 0);
        }
    }
}

// ---------------- causal flash attention: paired q-tiles {i, 31-i} per block ----------------
// Uniform 33 tile-computations/block (no tail); K/V staging shared by both q-tiles.
__global__ __launch_bounds__(256) void k_attn(const u16* __restrict__ Qb, const u16* __restrict__ Kb,
                                              const u16* __restrict__ Vt, u16* __restrict__ Ao) {
    __shared__ __align__(16) u16 Ks[64][72];
    __shared__ __align__(16) u16 Vs[64][72];     // Vs[d][key]
    __shared__ __align__(16) u16 Ps[4][16][72];  // per-wave P tile [q][key] (wave-private)
    const int i = blockIdx.x, bh = blockIdx.y;
    const int qtA = i, qtB = 31 - i;             // qtB > qtA always (i < 16)
    const int t = threadIdx.x, wave = t >> 6, lane = t & 63;
    const int g = lane >> 4, lr = lane & 15;
    const size_t bhO = (size_t)bh * (2048 * 64);
    const int q0A = qtA * 64, q0B = qtB * 64;
    const int rowqA = q0A + wave * 16, rowqB = q0B + wave * 16;

    bf16x8 qfA0 = *(const bf16x8*)(Qb + bhO + (size_t)(rowqA + lr) * 64 + g * 8);
    bf16x8 qfA1 = *(const bf16x8*)(Qb + bhO + (size_t)(rowqA + lr) * 64 + 32 + g * 8);
    bf16x8 qfB0 = *(const bf16x8*)(Qb + bhO + (size_t)(rowqB + lr) * 64 + g * 8);
    bf16x8 qfB1 = *(const bf16x8*)(Qb + bhO + (size_t)(rowqB + lr) * 64 + 32 + g * 8);

    f32x4 accA[4], accB[4];
    float mA[4], lA[4], mB[4], lB[4];
    #pragma unroll
    for (int x = 0; x < 4; x++) {
        accA[x] = (f32x4){0.f,0.f,0.f,0.f}; accB[x] = (f32x4){0.f,0.f,0.f,0.f};
        mA[x] = -INFINITY; lA[x] = 0.f; mB[x] = -INFINITY; lB[x] = 0.f;
    }

    const int sr0 = t >> 3,         sj0 = t & 7;
    const int sr1 = (t + 256) >> 3, sj1 = (t + 256) & 7;
    const u16* gK0 = Kb + bhO + (size_t)sr0 * 64 + sj0 * 8;
    const u16* gK1 = Kb + bhO + (size_t)sr1 * 64 + sj1 * 8;
    const u16* gV0 = Vt + bhO + (size_t)sr0 * 2048 + sj0 * 8;
    const u16* gV1 = Vt + bhO + (size_t)sr1 * 2048 + sj1 * 8;

    // prologue: prefetch tile 0 into registers
    uint4 pk0 = *(const uint4*)(gK0);
    uint4 pk1 = *(const uint4*)(gK1);
    uint4 pv0 = *(const uint4*)(gV0);
    uint4 pv1 = *(const uint4*)(gV1);

    for (int kt = 0; kt <= qtB; ++kt) {
        const int k0 = kt * 64;
        __syncthreads();  // previous iteration's LDS reads done before restaging
        *(uint4*)&Ks[sr0][sj0 * 8] = pk0;
        *(uint4*)&Ks[sr1][sj1 * 8] = pk1;
        *(uint4*)&Vs[sr0][sj0 * 8] = pv0;
        *(uint4*)&Vs[sr1][sj1 * 8] = pv1;
        __syncthreads();

        if (kt < qtB) {   // issue next tile's loads now; latency hides under compute
            const size_t kn = (size_t)(k0 + 64);
            pk0 = *(const uint4*)(gK0 + kn * 64);
            pk1 = *(const uint4*)(gK1 + kn * 64);
            pv0 = *(const uint4*)(gV0 + kn);
            pv1 = *(const uint4*)(gV1 + kn);
        }

        if (kt <= qtA)    // tile A active while kt within its causal range
            attn_tile(Ks, Vs, Ps[wave], g, lr, rowqA, k0, kt == qtA, qfA0, qfA1, accA, mA, lA);
        attn_tile(Ks, Vs, Ps[wave], g, lr, rowqB, k0, kt == qtB, qfB0, qfB1, accB, mB, lB);
    }

    const int b = bh >> 4, h = bh & 15;
    #pragma unroll
    for (int di = 0; di < 4; di++)
        #pragma unroll
        for (int r = 0; r < 4; r++) {
            int sA = rowqA + g * 4 + r;
            int sB = rowqB + g * 4 + r;
            Ao[((size_t)(b * 2048 + sA)) * 1024 + h * 64 + di * 16 + lr] = f2bf(accA[di][r] / lA[r]);
            Ao[((size_t)(b * 2048 + sB)) * 1024 + h * 64 + di * 16 + lr] = f2bf(accB[di][r] / lB[r]);
        }
}

// ---------------- output projection: out = Ao @ Wp + b (fp32 out) ----------------
__global__ __launch_bounds__(256) void k_gemm_proj(const u16* __restrict__ Ao, const u16* __restrict__ Wpb,
                                                   const float* __restrict__ b_proj, float* __restrict__ out) {
    f32x4 acc[4][4];
    const int m0 = blockIdx.y * 128, n0 = blockIdx.x * 128;
    gemm128_mainloop(Ao, Wpb, m0, n0, acc);
    const int lane = threadIdx.x & 63, wave = threadIdx.x >> 6;
    const int wr = wave >> 1, wc = wave & 1, g = lane >> 4, lr = lane & 15;
    #pragma unroll
    for (int mi = 0; mi < 4; mi++)
        #pragma unroll
        for (int ni = 0; ni < 4; ni++)
            #pragma unroll
            for (int r = 0; r < 4; r++) {
                int m = m0 + wr * 64 + mi * 16 + g * 4 + r;
                int n = n0 + wc * 64 + ni * 16 + lr;
                out[(size_t)m * 1024 + n] = acc[mi][ni][r] + b_proj[n];
            }
}

extern "C" void kernel_launch(void* const* d_in, const int* in_sizes, int n_in,
                              void* d_out, int out_size, void* d_ws, size_t ws_size,
                              hipStream_t stream) {
    const float* hidden = (const float*)d_in[0];
    const float* lora   = (const float*)d_in[1];
    const float* w_attn = (const float*)d_in[2];
    const float* b_attn = (const float*)d_in[3];
    const float* w_proj = (const float*)d_in[4];
    const float* b_proj = (const float*)d_in[5];
    float* out = (float*)d_out;

    char* ws = (char*)d_ws;
    u16* Xb  = (u16*)(ws + 0x0);        // 4096x1024 bf16 (reused as Ao after QKV GEMM)
    u16* Wab = (u16*)(ws + 0x800000);   // w_attn^T  [3072][1024] bf16
    u16* Wpb = (u16*)(ws + 0xE00000);   // w_proj^T  [1024][1024] bf16
    u16* Qb  = (u16*)(ws + 0x1000000);  // [B,H,S,64] bf16 (pre-scaled by 0.125)
    u16* Kb  = (u16*)(ws + 0x1800000);  // [B,H,S,64] bf16
    u16* Vt  = (u16*)(ws + 0x2000000);  // [B,H,64,S] bf16
    u16* Ao  = Xb;                      // merged attention output [B,S,1024] bf16

    k_convert<<<1024, 256, 0, stream>>>(hidden, Xb, (2 * 2048 * 1024) / 4);
    k_tconv<<<dim3(96, 32), dim3(32, 8), 0, stream>>>(w_attn, Wab, 1024, 3072);
    k_tconv<<<dim3(32, 32), dim3(32, 8), 0, stream>>>(w_proj, Wpb, 1024, 1024);
    k_gemm_qkv<<<dim3(24, 32), 256, 0, stream>>>(Xb, Wab, lora, b_attn, Qb, Kb, Vt);
    k_attn<<<dim3(16, 32), 256, 0, stream>>>(Qb, Kb, Vt, Ao);
    k_gemm_proj<<<dim3(8, 32), 256, 0, stream>>>(Ao, Wpb, b_proj, out);
}